// Round 2
// baseline (243.536 us; speedup 1.0000x reference)
//
#include <hip/hip_runtime.h>

// Problem constants (B, C, H, W = 64, 2048, 24, 8; NUM_IDS = 751)
#define BB 64
#define CC 2048
#define HWN 192          // H*W
#define HW4 48           // HW in float4
#define NCHUNK 16        // channel chunks per sample
#define CCHUNK 128       // CC / NCHUNK
#define TPB 384          // 8 channel-lanes x 48 hw4 positions; 6 waves/block
#define CLANES 8         // TPB / HW4

// ws layout (floats): heat[64*192] | cnt[64] (int) | heatN[64*192]
#define HEAT_OFF  0
#define CNT_OFF   (BB * HWN)          // 12288
#define HEATN_OFF (BB * HWN + BB)     // 12352

// ---- Kernel A: chunked dot -> atomic heat; last block per sample normalizes ----
// grid = 1024 (b*16 + k), block = 384.
__global__ void __launch_bounds__(TPB) heat_atomic_kernel(
    const float* __restrict__ f,
    const float* __restrict__ w,
    const int* __restrict__ pids,
    float* __restrict__ ws)
{
    float* heat  = ws + HEAT_OFF;
    int*   cnt   = (int*)(ws + CNT_OFF);
    float* heatN = ws + HEATN_OFF;

    const int blk = blockIdx.x;
    const int b = blk >> 4;            // sample
    const int k = blk & (NCHUNK - 1);  // channel chunk
    const int tid = threadIdx.x;       // 0..383
    const int hw4 = tid % HW4;         // 0..47
    const int cl  = tid / HW4;         // 0..7

    __shared__ float wsm[CCHUNK];
    __shared__ __align__(16) float4 red[TPB];
    __shared__ int s_last;
    __shared__ float s_mn, s_mx;

    const int row = pids[b];
    if (tid < CCHUNK) wsm[tid] = w[(size_t)row * CC + (size_t)k * CCHUNK + tid];
    __syncthreads();

    const size_t base = ((size_t)b * CC + (size_t)k * CCHUNK) * HW4;  // float4 units
    const float4* fb4 = (const float4*)f + base;

    float4 acc = make_float4(0.f, 0.f, 0.f, 0.f);
#pragma unroll 8
    for (int c = cl; c < CCHUNK; c += CLANES) {
        float4 v = fb4[(size_t)c * HW4 + hw4];
        float wv = wsm[c];
        acc.x = fmaf(wv, v.x, acc.x);
        acc.y = fmaf(wv, v.y, acc.y);
        acc.z = fmaf(wv, v.z, acc.z);
        acc.w = fmaf(wv, v.w, acc.w);
    }
    red[tid] = acc;
    __syncthreads();
    if (tid < HW4) {
        float4 s = red[tid];
#pragma unroll
        for (int j = 1; j < CLANES; ++j) {
            float4 a = red[tid + j * HW4];
            s.x += a.x; s.y += a.y; s.z += a.z; s.w += a.w;
        }
        float* hp = heat + (size_t)b * HWN + hw4 * 4;
        atomicAdd(hp + 0, s.x);
        atomicAdd(hp + 1, s.y);
        atomicAdd(hp + 2, s.z);
        atomicAdd(hp + 3, s.w);
    }
    __syncthreads();                   // all atomics of this block issued & drained
    if (tid == 0) {
        __threadfence();               // release our heat adds device-wide
        int old = atomicAdd(&cnt[b], 1);
        s_last = (old == NCHUNK - 1);
    }
    __syncthreads();
    if (!s_last) return;               // uniform across block

    // ---- last arriving block for sample b: min/max + normalize ----
    float v = 0.f;
    if (tid < HWN)
        v = atomicAdd(&heat[(size_t)b * HWN + tid], 0.0f);  // coherent read
    float* vals = (float*)red;         // red is dead; reuse as scratch
    if (tid < HWN) vals[tid] = v;
    __syncthreads();
    if (tid < 64) {
        float m0 = vals[tid], m1 = vals[tid + 64], m2 = vals[tid + 128];
        float mn = fminf(m0, fminf(m1, m2));
        float mx = fmaxf(m0, fmaxf(m1, m2));
        for (int off = 32; off > 0; off >>= 1) {
            mn = fminf(mn, __shfl_down(mn, off));
            mx = fmaxf(mx, __shfl_down(mx, off));
        }
        if (tid == 0) { s_mn = mn; s_mx = mx; }
    }
    __syncthreads();
    if (tid < HWN) {
        const float mn = s_mn, mx = s_mx;
        // reference: normalize only if max != 0
        heatN[(size_t)b * HWN + tid] = (mx != 0.f) ? (v - mn) / (mx - mn) : v;
    }
}

// ---- Kernel B: pure stream: out = f * heatN (no prologue, no syncs) ----
// grid = 1024 (b*16 + k), block = 384. hw4 = tid%48 is loop-invariant.
__global__ void __launch_bounds__(TPB) scale_kernel(
    const float* __restrict__ f,
    const float* __restrict__ ws,
    float* __restrict__ out)
{
    const float* heatN = ws + HEATN_OFF;
    const int blk = blockIdx.x;
    const int b = blk >> 4;
    const int k = blk & (NCHUNK - 1);
    const int tid = threadIdx.x;
    const int hw4 = tid % HW4;
    const int cl  = tid / HW4;

    const float4 hv = ((const float4*)(heatN + (size_t)b * HWN))[hw4];

    const size_t base = ((size_t)b * CC + (size_t)k * CCHUNK) * HW4;  // float4 units
    const float4* fb4 = (const float4*)f + base;
    float4* ob4 = (float4*)out + base;

#pragma unroll 8
    for (int c = cl; c < CCHUNK; c += CLANES) {
        const size_t idx = (size_t)c * HW4 + hw4;
        float4 x = fb4[idx];
        x.x *= hv.x; x.y *= hv.y; x.z *= hv.z; x.w *= hv.w;
        ob4[idx] = x;
    }
}

extern "C" void kernel_launch(void* const* d_in, const int* in_sizes, int n_in,
                              void* d_out, int out_size, void* d_ws, size_t ws_size,
                              hipStream_t stream) {
    const float* features = (const float*)d_in[0];   // [64,2048,24,8] f32
    const float* weight   = (const float*)d_in[1];   // [751,2048] f32
    const int*   pids     = (const int*)d_in[2];     // [64] int
    float* out = (float*)d_out;                      // [64,2048,24,8] f32
    float* ws  = (float*)d_ws;

    // zero heat accumulators + arrival counters (49.4 KB)
    hipMemsetAsync(d_ws, 0, (size_t)(BB * HWN + BB) * sizeof(float), stream);

    heat_atomic_kernel<<<BB * NCHUNK, TPB, 0, stream>>>(features, weight, pids, ws);
    scale_kernel<<<BB * NCHUNK, TPB, 0, stream>>>(features, ws, out);
}

// Round 4
// 197.430 us; speedup vs baseline: 1.2335x; 1.2335x over previous
//
#include <hip/hip_runtime.h>

// Problem constants (B, C, H, W = 64, 2048, 24, 8; NUM_IDS = 751)
#define BB 64
#define CC 2048
#define HWN 192          // H*W
#define HW4 48           // HW in float4
#define NCHUNK 16        // channel chunks per sample
#define CCHUNK 128       // CC / NCHUNK
#define TPB 384          // 8 channel-lanes x 48 hw4 positions; 6 waves/block
#define CLANES 8         // TPB / HW4

// native vector type for nontemporal builtins (HIP float4 is a class type)
typedef float f32x4 __attribute__((ext_vector_type(4)));

// ws layout (floats): partial[64*16*192] | heatN[64*192]
#define PART_OFF  0
#define HEATN_OFF (BB * NCHUNK * HWN)   // 196608

// ---- Kernel A: partial heat per (sample, 128-channel chunk) ----
// grid = 1024 (b*16 + k), block = 384. Loads are linear: idx = i*384 + tid.
__global__ void __launch_bounds__(TPB) heat_partial_kernel(
    const float* __restrict__ f,
    const float* __restrict__ w,
    const int* __restrict__ pids,
    float* __restrict__ ws)
{
    float* partial = ws + PART_OFF;

    const int blk = blockIdx.x;
    const int b = blk >> 4;            // sample
    const int k = blk & (NCHUNK - 1);  // channel chunk
    const int tid = threadIdx.x;       // 0..383
    const int hw4 = tid % HW4;         // 0..47
    const int cl  = tid / HW4;         // 0..7

    __shared__ float wsm[CCHUNK];
    __shared__ __align__(16) float4 red[TPB];

    const int row = pids[b];
    if (tid < CCHUNK) wsm[tid] = w[(size_t)row * CC + (size_t)k * CCHUNK + tid];
    __syncthreads();

    const size_t base = ((size_t)b * CC + (size_t)k * CCHUNK) * HW4;  // float4 units
    const float4* fb4 = (const float4*)f + base;

    float4 acc = make_float4(0.f, 0.f, 0.f, 0.f);
#pragma unroll
    for (int i = 0; i < CCHUNK / CLANES; ++i) {        // 16 iterations
        float4 v = fb4[(size_t)i * TPB + tid];         // perfectly linear
        float wv = wsm[cl + i * CLANES];               // broadcast within 48-group
        acc.x = fmaf(wv, v.x, acc.x);
        acc.y = fmaf(wv, v.y, acc.y);
        acc.z = fmaf(wv, v.z, acc.z);
        acc.w = fmaf(wv, v.w, acc.w);
    }
    red[tid] = acc;
    __syncthreads();
    if (tid < HW4) {
        float4 s = red[tid];
#pragma unroll
        for (int j = 1; j < CLANES; ++j) {
            float4 a = red[tid + j * HW4];
            s.x += a.x; s.y += a.y; s.z += a.z; s.w += a.w;
        }
        ((float4*)partial)[(size_t)(b * NCHUNK + k) * HW4 + tid] = s;
    }
}

// ---- Kernel A2: per-sample reduce of 16 partials + min/max + normalize ----
// grid = 64 (one block per sample), block = 192.
__global__ void __launch_bounds__(HWN) normalize_kernel(
    float* __restrict__ ws)
{
    const float* partial = ws + PART_OFF;
    float* heatN = ws + HEATN_OFF;

    const int b = blockIdx.x;
    const int tid = threadIdx.x;       // 0..191

    __shared__ float vals[HWN];
    __shared__ float s_mn, s_mx;

    const float* pb = partial + (size_t)b * NCHUNK * HWN + tid;
    float v = 0.f;
#pragma unroll
    for (int kk = 0; kk < NCHUNK; ++kk) v += pb[kk * HWN];
    vals[tid] = v;
    __syncthreads();

    if (tid < 64) {
        float m0 = vals[tid], m1 = vals[tid + 64], m2 = vals[tid + 128];
        float mn = fminf(m0, fminf(m1, m2));
        float mx = fmaxf(m0, fmaxf(m1, m2));
        for (int off = 32; off > 0; off >>= 1) {
            mn = fminf(mn, __shfl_down(mn, off));
            mx = fmaxf(mx, __shfl_down(mx, off));
        }
        if (tid == 0) { s_mn = mn; s_mx = mx; }
    }
    __syncthreads();

    const float mn = s_mn, mx = s_mx;
    // reference: normalize only if max != 0
    heatN[(size_t)b * HWN + tid] = (mx != 0.f) ? (v - mn) / (mx - mn) : v;
}

// ---- Kernel B: pure stream: out = f * heatN. No prologue, no syncs. ----
// grid = 1024 (b*16 + k), block = 384. hw4 = tid%48 is loop-invariant.
__global__ void __launch_bounds__(TPB) scale_kernel(
    const float* __restrict__ f,
    const float* __restrict__ ws,
    float* __restrict__ out)
{
    const float* heatN = ws + HEATN_OFF;
    const int blk = blockIdx.x;
    const int b = blk >> 4;
    const int k = blk & (NCHUNK - 1);
    const int tid = threadIdx.x;
    const int hw4 = tid % HW4;

    const f32x4 hv = ((const f32x4*)(heatN + (size_t)b * HWN))[hw4];

    const size_t base = ((size_t)b * CC + (size_t)k * CCHUNK) * HW4;  // float4 units
    const f32x4* fb4 = (const f32x4*)f + base;
    f32x4* ob4 = (f32x4*)out + base;

#pragma unroll
    for (int i = 0; i < (CCHUNK * HW4) / TPB; ++i) {   // 16 iterations, linear
        const size_t idx = (size_t)i * TPB + tid;
        f32x4 x = fb4[idx];
        x *= hv;
        __builtin_nontemporal_store(x, &ob4[idx]);     // out never re-read
    }
}

extern "C" void kernel_launch(void* const* d_in, const int* in_sizes, int n_in,
                              void* d_out, int out_size, void* d_ws, size_t ws_size,
                              hipStream_t stream) {
    const float* features = (const float*)d_in[0];   // [64,2048,24,8] f32
    const float* weight   = (const float*)d_in[1];   // [751,2048] f32
    const int*   pids     = (const int*)d_in[2];     // [64] int
    float* out = (float*)d_out;                      // [64,2048,24,8] f32
    float* ws  = (float*)d_ws;

    heat_partial_kernel<<<BB * NCHUNK, TPB, 0, stream>>>(features, weight, pids, ws);
    normalize_kernel<<<BB, HWN, 0, stream>>>(ws);
    scale_kernel<<<BB * NCHUNK, TPB, 0, stream>>>(features, ws, out);
}